// Round 3
// baseline (316.494 us; speedup 1.0000x reference)
//
#include <hip/hip_runtime.h>
#include <hip/hip_bf16.h>

#define BATCH 128
#define WIDTH 8192
#define DIM   64
#define FILT  32
#define KSZ   3
#define WOUT  8190
#define WT    126      // 65*126 = 8190 exactly -> no output-range masking vs WOUT
#define NBX   65
#define XR    128      // staged rows; w0+127 <= 8191 for every tile -> no load guards

typedef __attribute__((ext_vector_type(8))) _Float16 f16x8;
typedef __attribute__((ext_vector_type(4))) float f32x4;

__device__ inline unsigned encf(float f) {
  unsigned u = __float_as_uint(f);
  return (u & 0x80000000u) ? ~u : (u | 0x80000000u);
}
__device__ inline float decf(unsigned u) {
  unsigned b = (u & 0x80000000u) ? (u & 0x7fffffffu) : ~u;
  return __uint_as_float(b);
}

__global__ void init_mm(unsigned* mm) {
  int t = threadIdx.x;
  if (t < BATCH) { mm[2*t] = 0u; mm[2*t+1] = 0xFFFFFFFFu; }
}

// PASS 0: conv -> per-sample min/max atomics. PASS 1: conv -> normalize -> out.
// Conv accumulators are bit-identical across passes (same unrolled dataflow).
template<int PASS>
__global__ __launch_bounds__(256, 3)
void conv_pass(const float* __restrict__ x, const float* __restrict__ ker,
               float* __restrict__ out, unsigned* __restrict__ mm)
{
  // xs: fp32 [row][64 floats], rows 0..127 DMA'd linear with 16B-slot XOR swizzle
  // (content: xs[row][slot] = x[row][slot ^ (row&7)]); rows 128..129 zeroed
  // (touched only by lanes whose output rows are masked out).
  __shared__ __align__(16) float xs[(XR + 2) * DIM];
  __shared__ __align__(16) short ks[KSZ * FILT * DIM];  // f16 [k][f][d], XOR-swizzled

  const int t  = threadIdx.x;
  const int l  = t & 63;
  const int wv = t >> 6;
  const int b  = blockIdx.y;
  const int w0 = blockIdx.x * WT;

  // ---- weights: fp32 [k][d][f] -> f16 LDS [k][f][d], b128 writes (bank-balanced)
  #pragma unroll
  for (int i = 0; i < 3; ++i) {
    int c  = i * 256 + t;            // 768 chunks of 8 consecutive d
    int k  = c >> 8, rem = c & 255;
    int f  = rem >> 3;
    int d0 = (rem & 7) * 8;
    f16x8 hv;
    #pragma unroll
    for (int d = 0; d < 8; ++d)
      hv[d] = (_Float16)ker[(k * DIM + d0 + d) * FILT + f];
    int byte = ((k * FILT + f) * DIM + d0) * 2;
    byte ^= (f & 7) << 4;
    *reinterpret_cast<f16x8*>(&ks[byte >> 1]) = hv;
  }

  // ---- zero halo rows 128,129 (512 B)
  if (t < 32) {
    int row = XR + (t >> 4), slot = t & 15;
    *reinterpret_cast<f32x4*>(&xs[row * DIM + slot * 4]) = (f32x4){0.f, 0.f, 0.f, 0.f};
  }

  // ---- x rows [w0, w0+128): direct-to-LDS DMA, per-lane source pre-swizzled.
  // Each issue: 1 KB (64 lanes x 16B), LDS dest wave-uniform base + lane*16.
  const float* xb = x + ((long)b * WIDTH + w0) * DIM;
  #pragma unroll
  for (int j = 0; j < 8; ++j) {
    int off    = (wv * 8 + j) * 1024;        // linear LDS byte offset of this chunk
    int L      = off + l * 16;               // this lane's LDS byte
    int row    = L >> 8;
    int slot_l = (L >> 4) & 15;
    int slot_g = slot_l ^ (row & 7);         // inverse swizzle on the SOURCE
    const float* src = xb + row * DIM + slot_g * 4;
    __builtin_amdgcn_global_load_lds(
        (const __attribute__((address_space(1))) void*)src,
        (__attribute__((address_space(3))) void*)((char*)xs + off),
        16, 0, 0);
  }
  __syncthreads();   // compiler drains vmcnt(0)+lgkmcnt(0) here

  // ---- B fragments: 12 frags x 4 VGPR (f16)
  f16x8 Bf[KSZ][2][2];
  #pragma unroll
  for (int s = 0; s < KSZ; ++s)
    #pragma unroll
    for (int kh = 0; kh < 2; ++kh)
      #pragma unroll
      for (int nt = 0; nt < 2; ++nt) {
        int f  = nt * 16 + (l & 15);
        int d0 = kh * 32 + (l >> 4) * 8;
        int byte = ((s * FILT + f) * DIM + d0) * 2;
        byte ^= (f & 7) << 4;
        Bf[s][kh][nt] = *reinterpret_cast<const f16x8*>(&ks[byte >> 1]);
      }

  f32x4 acc[2][2];
  #pragma unroll
  for (int mt = 0; mt < 2; ++mt)
    #pragma unroll
    for (int nt = 0; nt < 2; ++nt)
      acc[mt][nt] = (f32x4){0.f, 0.f, 0.f, 0.f};

  // ---- main loop: wave owns output rows [wv*32, wv*32+32)
  #pragma unroll
  for (int s = 0; s < KSZ; ++s) {
    #pragma unroll
    for (int kh = 0; kh < 2; ++kh) {
      f16x8 a[2];
      #pragma unroll
      for (int mt = 0; mt < 2; ++mt) {
        int row = wv * 32 + mt * 16 + (l & 15) + s;
        int sg  = kh * 8 + (l >> 4) * 2;     // even 16B-slot index
        int rb  = row & 7;
        f32x4 u0 = *reinterpret_cast<const f32x4*>(&xs[row * DIM + ((sg    ) ^ rb) * 4]);
        f32x4 u1 = *reinterpret_cast<const f32x4*>(&xs[row * DIM + ((sg + 1) ^ rb) * 4]);
        f16x8 av;
        av[0] = (_Float16)u0.x; av[1] = (_Float16)u0.y;
        av[2] = (_Float16)u0.z; av[3] = (_Float16)u0.w;
        av[4] = (_Float16)u1.x; av[5] = (_Float16)u1.y;
        av[6] = (_Float16)u1.z; av[7] = (_Float16)u1.w;
        a[mt] = av;
      }
      #pragma unroll
      for (int mt = 0; mt < 2; ++mt)
        #pragma unroll
        for (int nt = 0; nt < 2; ++nt)
          acc[mt][nt] = __builtin_amdgcn_mfma_f32_16x16x32_f16(
              a[mt], Bf[s][kh][nt], acc[mt][nt], 0, 0, 0);
    }
  }

  if (PASS == 0) {
    float mx = -INFINITY, mn = INFINITY;
    #pragma unroll
    for (int mt = 0; mt < 2; ++mt)
      #pragma unroll
      for (int nt = 0; nt < 2; ++nt)
        #pragma unroll
        for (int r = 0; r < 4; ++r) {
          int wl = wv * 32 + mt * 16 + (l >> 4) * 4 + r;  // C-row = (lane>>4)*4+reg
          if (wl < WT) {
            float v = acc[mt][nt][r];
            mx = fmaxf(mx, v); mn = fminf(mn, v);
          }
        }
    #pragma unroll
    for (int off = 32; off > 0; off >>= 1) {
      mx = fmaxf(mx, __shfl_down(mx, off));
      mn = fminf(mn, __shfl_down(mn, off));
    }
    if (l == 0) {
      atomicMax(&mm[2*b],   encf(mx));
      atomicMin(&mm[2*b+1], encf(mn));
    }
  } else {
    float mxv = decf(mm[2*b]);
    float mnv = decf(mm[2*b+1]);
    float rs = 1.0f / (mxv - mnv);
    #pragma unroll
    for (int mt = 0; mt < 2; ++mt)
      #pragma unroll
      for (int nt = 0; nt < 2; ++nt)
        #pragma unroll
        for (int r = 0; r < 4; ++r) {
          int wl = wv * 32 + mt * 16 + (l >> 4) * 4 + r;
          if (wl < WT) {
            int f = nt * 16 + (l & 15);
            out[((long)b * WOUT + (w0 + wl)) * FILT + f] = (acc[mt][nt][r] - mnv) * rs;
          }
        }
  }
}

extern "C" void kernel_launch(void* const* d_in, const int* in_sizes, int n_in,
                              void* d_out, int out_size, void* d_ws, size_t ws_size,
                              hipStream_t stream) {
  const float* x   = (const float*)d_in[0];
  const float* ker = (const float*)d_in[1];
  float* out = (float*)d_out;
  unsigned* mm = (unsigned*)d_ws;   // 128 x {max,min} encoded uints (1 KB)

  init_mm<<<dim3(1), dim3(256), 0, stream>>>(mm);
  dim3 grid(NBX, BATCH);
  conv_pass<0><<<grid, dim3(256), 0, stream>>>(x, ker, nullptr, mm);
  conv_pass<1><<<grid, dim3(256), 0, stream>>>(x, ker, out, mm);
}

// Round 4
// 166.294 us; speedup vs baseline: 1.9032x; 1.9032x over previous
//
#include <hip/hip_runtime.h>
#include <hip/hip_bf16.h>

#define BATCH  128
#define WIDTH  8192
#define DIM    64
#define FILT   32
#define KSZ    3
#define WOUT   8190
#define WT     126     // output rows per tile; 65*126 = 8190 exactly
#define TPB    5       // tiles per block
#define NSPLIT 13      // 13*5 = 65 tiles
#define XR     128     // staged rows per tile (rows 128..129 of buffer: garbage, masked)

typedef __attribute__((ext_vector_type(8))) _Float16 f16x8;
typedef __attribute__((ext_vector_type(4))) float f32x4;

__device__ inline unsigned encf(float f) {
  unsigned u = __float_as_uint(f);
  return (u & 0x80000000u) ? ~u : (u | 0x80000000u);
}
__device__ inline float decf(unsigned u) {
  unsigned b = (u & 0x80000000u) ? (u & 0x7fffffffu) : ~u;
  return __uint_as_float(b);
}

__global__ void init_mm(unsigned* mm) {
  int t = threadIdx.x;
  if (t < BATCH) { mm[2*t] = 0u; mm[2*t+1] = 0xFFFFFFFFu; }
}

// PASS 0: conv -> per-sample min/max atomics. PASS 1: conv -> normalize -> out.
// Accumulators are bit-identical across passes (same unrolled dataflow).
template<int PASS>
__global__ __launch_bounds__(256, 2)
void conv_pass(const float* __restrict__ x, const float* __restrict__ ker,
               float* __restrict__ out, unsigned* __restrict__ mm)
{
  // Double-buffered x tiles: fp32 [row][64], rows 0..127 DMA'd linear with
  // 16B-slot XOR swizzle (content: xs[f][row][slot] = x[row][slot ^ (row&7)]).
  // Rows 128..129 hold stale data; only masked-out lanes read them.
  __shared__ __align__(16) float xs[2][(XR + 2) * DIM];
  __shared__ __align__(16) short ks[KSZ * FILT * DIM];  // f16 [k][f][d], XOR-swizzled

  const int t  = threadIdx.x;
  const int l  = t & 63;
  const int wv = t >> 6;
  const int b  = blockIdx.y;
  const int tile0 = blockIdx.x * TPB;

  // ---- weights: fp32 [k][d][f] COALESCED read -> f16 LDS [k][f][d], swizzled
  #pragma unroll
  for (int i = 0; i < 24; ++i) {
    int idx = t + i * 256;              // 6144 elements, consecutive lanes adjacent
    int k = idx >> 11, rem = idx & 2047;
    int d = rem >> 5,  f = rem & 31;
    _Float16 hv = (_Float16)ker[idx];
    int byte = ((k * FILT + f) * DIM + d) * 2;
    byte ^= (f & 7) << 4;
    ks[byte >> 1] = __builtin_bit_cast(short, hv);
  }

  const float* xbase = x + (long)b * WIDTH * DIM;

  // STAGE: 8 direct-to-LDS DMA issues per wave (1 KB each), source pre-swizzled.
  auto stage = [&](int buf, int tile) {
    const float* xb = xbase + (long)(tile0 + tile) * WT * DIM;
    char* lb = (char*)&xs[buf][0];
    #pragma unroll
    for (int j = 0; j < 8; ++j) {
      int off  = (wv * 8 + j) * 1024;       // linear LDS byte offset of this chunk
      int L    = off + l * 16;
      int row  = L >> 8;
      int slot = ((L >> 4) & 15) ^ (row & 7);
      __builtin_amdgcn_global_load_lds(
          (const __attribute__((address_space(1))) void*)(xb + row * DIM + slot * 4),
          (__attribute__((address_space(3))) void*)(lb + off), 16, 0, 0);
    }
  };

  stage(0, 0);
  __syncthreads();   // drains weight ds_writes + buf0 DMA

  // ---- B fragments: 12 frags x 4 VGPR (f16)
  f16x8 Bf[KSZ][2][2];
  #pragma unroll
  for (int s = 0; s < KSZ; ++s)
    #pragma unroll
    for (int kh = 0; kh < 2; ++kh)
      #pragma unroll
      for (int nt = 0; nt < 2; ++nt) {
        int f  = nt * 16 + (l & 15);
        int d0 = kh * 32 + (l >> 4) * 8;
        int byte = ((s * FILT + f) * DIM + d0) * 2;
        byte ^= (f & 7) << 4;
        Bf[s][kh][nt] = *reinterpret_cast<const f16x8*>(&ks[byte >> 1]);
      }

  float mx = -INFINITY, mn = INFINITY;          // PASS 0 running min/max
  float mnv = 0.f, rs = 0.f;                    // PASS 1 normalization
  if (PASS == 1) {
    float mxv = decf(mm[2*b]);
    mnv = decf(mm[2*b+1]);
    rs = 1.0f / (mxv - mnv);
  }

  int cur = 0;
  for (int it = 0; it < TPB; ++it) {
    if (it + 1 < TPB) stage(cur ^ 1, it + 1);   // next tile flies during compute

    const float* xl = &xs[cur][0];
    f32x4 acc[2][2];
    #pragma unroll
    for (int mt = 0; mt < 2; ++mt)
      #pragma unroll
      for (int nt = 0; nt < 2; ++nt)
        acc[mt][nt] = (f32x4){0.f, 0.f, 0.f, 0.f};

    // wave owns output rows [wv*32, wv*32+32) of this tile
    #pragma unroll
    for (int s = 0; s < KSZ; ++s) {
      #pragma unroll
      for (int kh = 0; kh < 2; ++kh) {
        f16x8 a[2];
        #pragma unroll
        for (int mt = 0; mt < 2; ++mt) {
          int row = wv * 32 + mt * 16 + (l & 15) + s;
          int sg  = kh * 8 + (l >> 4) * 2;      // even 16B-slot index
          int rb  = row & 7;
          f32x4 u0 = *reinterpret_cast<const f32x4*>(&xl[row * DIM + ((sg    ) ^ rb) * 4]);
          f32x4 u1 = *reinterpret_cast<const f32x4*>(&xl[row * DIM + ((sg + 1) ^ rb) * 4]);
          f16x8 av;
          av[0] = (_Float16)u0.x; av[1] = (_Float16)u0.y;
          av[2] = (_Float16)u0.z; av[3] = (_Float16)u0.w;
          av[4] = (_Float16)u1.x; av[5] = (_Float16)u1.y;
          av[6] = (_Float16)u1.z; av[7] = (_Float16)u1.w;
          a[mt] = av;
        }
        #pragma unroll
        for (int mt = 0; mt < 2; ++mt)
          #pragma unroll
          for (int nt = 0; nt < 2; ++nt)
            acc[mt][nt] = __builtin_amdgcn_mfma_f32_16x16x32_f16(
                a[mt], Bf[s][kh][nt], acc[mt][nt], 0, 0, 0);
      }
    }

    if (PASS == 0) {
      #pragma unroll
      for (int mt = 0; mt < 2; ++mt)
        #pragma unroll
        for (int nt = 0; nt < 2; ++nt)
          #pragma unroll
          for (int r = 0; r < 4; ++r) {
            int wl = wv * 32 + mt * 16 + (l >> 4) * 4 + r;  // C-row = (lane>>4)*4+reg
            if (wl < WT) {
              float v = acc[mt][nt][r];
              mx = fmaxf(mx, v); mn = fminf(mn, v);
            }
          }
    } else {
      int w0 = (tile0 + it) * WT;
      #pragma unroll
      for (int mt = 0; mt < 2; ++mt)
        #pragma unroll
        for (int nt = 0; nt < 2; ++nt)
          #pragma unroll
          for (int r = 0; r < 4; ++r) {
            int wl = wv * 32 + mt * 16 + (l >> 4) * 4 + r;
            if (wl < WT) {
              int f = nt * 16 + (l & 15);
              out[((long)b * WOUT + (w0 + wl)) * FILT + f] = (acc[mt][nt][r] - mnv) * rs;
            }
          }
    }

    __syncthreads();   // publish staged buffer; all waves done reading xs[cur]
    cur ^= 1;
  }

  if (PASS == 0) {
    #pragma unroll
    for (int off = 32; off > 0; off >>= 1) {
      mx = fmaxf(mx, __shfl_down(mx, off));
      mn = fminf(mn, __shfl_down(mn, off));
    }
    if (l == 0) {
      atomicMax(&mm[2*b],   encf(mx));
      atomicMin(&mm[2*b+1], encf(mn));
    }
  }
}

extern "C" void kernel_launch(void* const* d_in, const int* in_sizes, int n_in,
                              void* d_out, int out_size, void* d_ws, size_t ws_size,
                              hipStream_t stream) {
  const float* x   = (const float*)d_in[0];
  const float* ker = (const float*)d_in[1];
  float* out = (float*)d_out;
  unsigned* mm = (unsigned*)d_ws;   // 128 x {max,min} encoded uints (1 KB)

  init_mm<<<dim3(1), dim3(256), 0, stream>>>(mm);
  dim3 grid(NSPLIT, BATCH);
  conv_pass<0><<<grid, dim3(256), 0, stream>>>(x, ker, nullptr, mm);
  conv_pass<1><<<grid, dim3(256), 0, stream>>>(x, ker, out, mm);
}

// Round 5
// 136.977 us; speedup vs baseline: 2.3106x; 1.2140x over previous
//
#include <hip/hip_runtime.h>
#include <hip/hip_bf16.h>

#define BATCH  128
#define WIDTH  8192
#define DIM    64
#define FILT   32
#define KSZ    3
#define WOUT   8190
#define RPW    30      // output rows per wave per tile
#define WT     120     // output rows per tile (4 waves)
#define TPB    18      // tiles per block
#define NBX    4       // NBX*TPB = 72 tiles >= ceil(8190/120) = 69

typedef __attribute__((ext_vector_type(8))) _Float16 f16x8;
typedef __attribute__((ext_vector_type(4))) float f32x4;

// PASS 0: conv -> per-block min/max to mm[(b*NBX+bx)*2]. PASS 1: conv -> normalize -> out.
// Accumulators bit-identical across passes (same unrolled dataflow).
template<int PASS>
__global__ __launch_bounds__(256, 2)
void conv_pass(const float* __restrict__ x, const float* __restrict__ ker,
               float* __restrict__ out, float* __restrict__ mm)
{
  // Per-wave private double-buffered x tiles: fp32 [buf][wave][32 rows][64].
  // DMA'd linear; content swizzled: xs[..][row][slot16] = x[row][slot16 ^ (row&7)].
  __shared__ __align__(16) float xs[2][4][32][DIM];   // 64 KB
  __shared__ __align__(16) short ks[KSZ * FILT * DIM]; // f16 [k][f][d], 12 KB
  __shared__ float red[8];

  const int t  = threadIdx.x;
  const int l  = t & 63;
  const int wv = t >> 6;
  const int b  = blockIdx.y;
  const int tile0 = blockIdx.x * TPB;
  const float* xb = x + (long)b * WIDTH * DIM;

  // Per-wave stage: 8 direct-to-LDS DMA (1 KB each) into this wave's region.
  // LDS dest is wave-uniform + lane*16 (HW rule); source pre-swizzled per lane.
  auto stage = [&](int bb, int tile) {
    long gw0 = (long)(tile0 + tile) * WT + wv * RPW;
    char* lb = (char*)&xs[bb][wv][0][0];
    #pragma unroll
    for (int j = 0; j < 8; ++j) {
      int row_l = j * 4 + (l >> 4);
      int slot  = (l & 15) ^ (row_l & 7);
      long gr = gw0 + row_l;
      if (gr > WIDTH - 1) gr = WIDTH - 1;   // tail-tile OOB guard (dup reads, L2-hot)
      __builtin_amdgcn_global_load_lds(
          (const __attribute__((address_space(1))) void*)(xb + gr * DIM + slot * 4),
          (__attribute__((address_space(3))) void*)(lb + j * 1024), 16, 0, 0);
    }
  };

  stage(0, 0);   // prologue prefetch; hides under weight staging

  // ---- weights: fp32 [k][d][f] coalesced -> f16 LDS [k][f][d], XOR-swizzled
  #pragma unroll
  for (int i = 0; i < 24; ++i) {
    int idx = t + i * 256;
    int k = idx >> 11, rem = idx & 2047;
    int d = rem >> 5,  f = rem & 31;
    _Float16 hv = (_Float16)ker[idx];
    int byte = ((k * FILT + f) * DIM + d) * 2;
    byte ^= (f & 7) << 4;
    ks[byte >> 1] = __builtin_bit_cast(short, hv);
  }
  __syncthreads();   // ONLY barrier before epilogue: weights + T0 DMA drained

  // ---- B fragments: 12 frags x 4 VGPR (f16)
  f16x8 Bf[KSZ][2][2];
  #pragma unroll
  for (int s = 0; s < KSZ; ++s)
    #pragma unroll
    for (int kh = 0; kh < 2; ++kh)
      #pragma unroll
      for (int nt = 0; nt < 2; ++nt) {
        int f  = nt * 16 + (l & 15);
        int d0 = kh * 32 + (l >> 4) * 8;
        int byte = ((s * FILT + f) * DIM + d0) * 2;
        byte ^= (f & 7) << 4;
        Bf[s][kh][nt] = *reinterpret_cast<const f16x8*>(&ks[byte >> 1]);
      }

  float mx = -INFINITY, mn = INFINITY;   // PASS 0
  float mnv = 0.f, rs = 0.f;             // PASS 1
  if (PASS == 1) {
    float mxv = -INFINITY; mnv = INFINITY;
    #pragma unroll
    for (int i = 0; i < NBX; ++i) {
      mxv = fmaxf(mxv, mm[(b * NBX + i) * 2]);
      mnv = fminf(mnv, mm[(b * NBX + i) * 2 + 1]);
    }
    rs = 1.0f / (mxv - mnv);
  }

  int cur = 0;
  for (int it = 0; it < TPB; ++it) {
    // T4: counted vmcnt — next tile's 8 loads stay in flight through compute.
    if (it + 1 < TPB) {
      stage(cur ^ 1, it + 1);
      asm volatile("s_waitcnt vmcnt(8)" ::: "memory");   // prev tile's 8 retired
    } else {
      asm volatile("s_waitcnt vmcnt(0)" ::: "memory");
    }
    __builtin_amdgcn_sched_barrier(0);   // rule #18: pin ds_reads after the wait

    const float* xl = &xs[cur][wv][0][0];
    f32x4 acc[2][2];
    #pragma unroll
    for (int mt = 0; mt < 2; ++mt)
      #pragma unroll
      for (int nt = 0; nt < 2; ++nt)
        acc[mt][nt] = (f32x4){0.f, 0.f, 0.f, 0.f};

    #pragma unroll
    for (int s = 0; s < KSZ; ++s) {
      #pragma unroll
      for (int kh = 0; kh < 2; ++kh) {
        f16x8 a[2];
        #pragma unroll
        for (int mt = 0; mt < 2; ++mt) {
          int r  = mt * 16 + (l & 15) + s;   // rows 32..33 bleed into neighbor: masked
          int sg = kh * 8 + (l >> 4) * 2;
          int rb = r & 7;
          f32x4 u0 = *reinterpret_cast<const f32x4*>(&xl[r * DIM + ((sg    ) ^ rb) * 4]);
          f32x4 u1 = *reinterpret_cast<const f32x4*>(&xl[r * DIM + ((sg + 1) ^ rb) * 4]);
          f16x8 av;
          av[0] = (_Float16)u0.x; av[1] = (_Float16)u0.y;
          av[2] = (_Float16)u0.z; av[3] = (_Float16)u0.w;
          av[4] = (_Float16)u1.x; av[5] = (_Float16)u1.y;
          av[6] = (_Float16)u1.z; av[7] = (_Float16)u1.w;
          a[mt] = av;
        }
        #pragma unroll
        for (int mt = 0; mt < 2; ++mt)
          #pragma unroll
          for (int nt = 0; nt < 2; ++nt)
            acc[mt][nt] = __builtin_amdgcn_mfma_f32_16x16x32_f16(
                a[mt], Bf[s][kh][nt], acc[mt][nt], 0, 0, 0);
      }
    }

    long w0t = (long)(tile0 + it) * WT + wv * RPW;
    if (PASS == 0) {
      #pragma unroll
      for (int mt = 0; mt < 2; ++mt)
        #pragma unroll
        for (int nt = 0; nt < 2; ++nt)
          #pragma unroll
          for (int r = 0; r < 4; ++r) {
            int wl = mt * 16 + (l >> 4) * 4 + r;   // C-row = (lane>>4)*4+reg
            long gr = w0t + wl;
            if (wl < RPW && gr < WOUT) {
              float v = acc[mt][nt][r];
              mx = fmaxf(mx, v); mn = fminf(mn, v);
            }
          }
    } else {
      #pragma unroll
      for (int mt = 0; mt < 2; ++mt)
        #pragma unroll
        for (int nt = 0; nt < 2; ++nt)
          #pragma unroll
          for (int r = 0; r < 4; ++r) {
            int wl = mt * 16 + (l >> 4) * 4 + r;
            long gr = w0t + wl;
            if (wl < RPW && gr < WOUT) {
              int f = nt * 16 + (l & 15);
              out[((long)b * WOUT + gr) * FILT + f] = (acc[mt][nt][r] - mnv) * rs;
            }
          }
    }
    cur ^= 1;
  }

  if (PASS == 0) {
    #pragma unroll
    for (int off = 32; off > 0; off >>= 1) {
      mx = fmaxf(mx, __shfl_down(mx, off));
      mn = fminf(mn, __shfl_down(mn, off));
    }
    if (l == 0) { red[wv * 2] = mx; red[wv * 2 + 1] = mn; }
    __syncthreads();
    if (t == 0) {
      float Mx = fmaxf(fmaxf(red[0], red[2]), fmaxf(red[4], red[6]));
      float Mn = fminf(fminf(red[1], red[3]), fminf(red[5], red[7]));
      mm[(b * NBX + blockIdx.x) * 2]     = Mx;
      mm[(b * NBX + blockIdx.x) * 2 + 1] = Mn;
    }
  }
}

extern "C" void kernel_launch(void* const* d_in, const int* in_sizes, int n_in,
                              void* d_out, int out_size, void* d_ws, size_t ws_size,
                              hipStream_t stream) {
  const float* x   = (const float*)d_in[0];
  const float* ker = (const float*)d_in[1];
  float* out = (float*)d_out;
  float* mm  = (float*)d_ws;   // 512 x {max,min} floats (4 KB), fully rewritten each call

  dim3 grid(NBX, BATCH);
  conv_pass<0><<<grid, dim3(256), 0, stream>>>(x, ker, nullptr, mm);
  conv_pass<1><<<grid, dim3(256), 0, stream>>>(x, ker, out, mm);
}

// Round 8
// 133.116 us; speedup vs baseline: 2.3776x; 1.0290x over previous
//
#include <hip/hip_runtime.h>
#include <hip/hip_bf16.h>

#define BATCH  128
#define WIDTH  8192
#define DIM    64
#define FILT   32
#define KSZ    3
#define WOUT   8190
#define RPW    30      // output rows per wave per tile
#define WT     120     // output rows per tile (4 waves)
#define TPB    18      // tiles per block
#define NBX    4       // NBX*TPB = 72 tiles >= ceil(8190/120) = 69

typedef __attribute__((ext_vector_type(8))) _Float16 f16x8;
typedef __attribute__((ext_vector_type(4))) float f32x4;

// Conv once: per-block min/max -> mm, raw f32 conv values -> cf (same flat
// layout as the final output: [b][w][f]).
__global__ __launch_bounds__(256, 2)
void conv_min(const float* __restrict__ x, const float* __restrict__ ker,
              float* __restrict__ cf, float* __restrict__ mm)
{
  // Per-wave private double-buffered x tiles: fp32 [buf][wave][32 rows][64].
  // DMA'd linear; content swizzled: xs[..][row][slot16] = x[row][slot16 ^ (row&7)].
  __shared__ __align__(16) float xs[2][4][32][DIM];   // 64 KB
  __shared__ __align__(16) short ks[KSZ * FILT * DIM]; // f16 [k][f][d], 12 KB
  __shared__ float red[8];

  const int t  = threadIdx.x;
  const int l  = t & 63;
  const int wv = t >> 6;
  const int b  = blockIdx.y;
  const int tile0 = blockIdx.x * TPB;
  const float* xb = x + (long)b * WIDTH * DIM;

  // Per-wave stage: 8 direct-to-LDS DMA (1 KB each) into this wave's region.
  auto stage = [&](int bb, int tile) {
    long gw0 = (long)(tile0 + tile) * WT + wv * RPW;
    char* lb = (char*)&xs[bb][wv][0][0];
    #pragma unroll
    for (int j = 0; j < 8; ++j) {
      int row_l = j * 4 + (l >> 4);
      int slot  = (l & 15) ^ (row_l & 7);
      long gr = gw0 + row_l;
      if (gr > WIDTH - 1) gr = WIDTH - 1;   // tail-tile OOB guard
      __builtin_amdgcn_global_load_lds(
          (const __attribute__((address_space(1))) void*)(xb + gr * DIM + slot * 4),
          (__attribute__((address_space(3))) void*)(lb + j * 1024), 16, 0, 0);
    }
  };

  stage(0, 0);   // prologue prefetch; hides under weight staging

  // ---- weights: fp32 [k][d][f] coalesced -> f16 LDS [k][f][d], XOR-swizzled
  #pragma unroll
  for (int i = 0; i < 24; ++i) {
    int idx = t + i * 256;
    int k = idx >> 11, rem = idx & 2047;
    int d = rem >> 5,  f = rem & 31;
    _Float16 hv = (_Float16)ker[idx];
    int byte = ((k * FILT + f) * DIM + d) * 2;
    byte ^= (f & 7) << 4;
    ks[byte >> 1] = __builtin_bit_cast(short, hv);
  }
  __syncthreads();   // only barrier before epilogue

  // ---- B fragments: 12 frags x 4 VGPR (f16)
  f16x8 Bf[KSZ][2][2];
  #pragma unroll
  for (int s = 0; s < KSZ; ++s)
    #pragma unroll
    for (int kh = 0; kh < 2; ++kh)
      #pragma unroll
      for (int nt = 0; nt < 2; ++nt) {
        int f  = nt * 16 + (l & 15);
        int d0 = kh * 32 + (l >> 4) * 8;
        int byte = ((s * FILT + f) * DIM + d0) * 2;
        byte ^= (f & 7) << 4;
        Bf[s][kh][nt] = *reinterpret_cast<const f16x8*>(&ks[byte >> 1]);
      }

  float mx = -INFINITY, mn = INFINITY;

  int cur = 0;
  for (int it = 0; it < TPB; ++it) {
    // T4: counted vmcnt — next tile's loads stay in flight through compute.
    if (it + 1 < TPB) {
      stage(cur ^ 1, it + 1);
      asm volatile("s_waitcnt vmcnt(8)" ::: "memory");
    } else {
      asm volatile("s_waitcnt vmcnt(0)" ::: "memory");
    }
    __builtin_amdgcn_sched_barrier(0);   // rule #18: pin ds_reads after the wait

    const float* xl = &xs[cur][wv][0][0];
    f32x4 acc[2][2];
    #pragma unroll
    for (int mt = 0; mt < 2; ++mt)
      #pragma unroll
      for (int nt = 0; nt < 2; ++nt)
        acc[mt][nt] = (f32x4){0.f, 0.f, 0.f, 0.f};

    #pragma unroll
    for (int s = 0; s < KSZ; ++s) {
      #pragma unroll
      for (int kh = 0; kh < 2; ++kh) {
        f16x8 a[2];
        #pragma unroll
        for (int mt = 0; mt < 2; ++mt) {
          int r  = mt * 16 + (l & 15) + s;   // rows 32..33 bleed into neighbor: masked
          int sg = kh * 8 + (l >> 4) * 2;
          int rb = r & 7;
          f32x4 u0 = *reinterpret_cast<const f32x4*>(&xl[r * DIM + ((sg    ) ^ rb) * 4]);
          f32x4 u1 = *reinterpret_cast<const f32x4*>(&xl[r * DIM + ((sg + 1) ^ rb) * 4]);
          f16x8 av;
          av[0] = (_Float16)u0.x; av[1] = (_Float16)u0.y;
          av[2] = (_Float16)u0.z; av[3] = (_Float16)u0.w;
          av[4] = (_Float16)u1.x; av[5] = (_Float16)u1.y;
          av[6] = (_Float16)u1.z; av[7] = (_Float16)u1.w;
          a[mt] = av;
        }
        #pragma unroll
        for (int mt = 0; mt < 2; ++mt)
          #pragma unroll
          for (int nt = 0; nt < 2; ++nt)
            acc[mt][nt] = __builtin_amdgcn_mfma_f32_16x16x32_f16(
                a[mt], Bf[s][kh][nt], acc[mt][nt], 0, 0, 0);
      }
    }

    // Epilogue: EXACT round-5 pass-1 addressing, storing raw conv value to cf,
    // plus the round-5 pass-0 min/max update. Nothing new.
    long w0t = (long)(tile0 + it) * WT + wv * RPW;
    #pragma unroll
    for (int mt = 0; mt < 2; ++mt)
      #pragma unroll
      for (int nt = 0; nt < 2; ++nt)
        #pragma unroll
        for (int r = 0; r < 4; ++r) {
          int wl = mt * 16 + (l >> 4) * 4 + r;   // C-row = (lane>>4)*4+reg
          long gr = w0t + wl;
          if (wl < RPW && gr < WOUT) {
            float v = acc[mt][nt][r];
            mx = fmaxf(mx, v); mn = fminf(mn, v);
            int f = nt * 16 + (l & 15);
            cf[((long)b * WOUT + gr) * FILT + f] = v;
          }
        }
    cur ^= 1;
  }

  #pragma unroll
  for (int off = 32; off > 0; off >>= 1) {
    mx = fmaxf(mx, __shfl_down(mx, off));
    mn = fminf(mn, __shfl_down(mn, off));
  }
  if (l == 0) { red[wv * 2] = mx; red[wv * 2 + 1] = mn; }
  __syncthreads();
  if (t == 0) {
    float Mx = fmaxf(fmaxf(red[0], red[2]), fmaxf(red[4], red[6]));
    float Mn = fminf(fminf(red[1], red[3]), fminf(red[5], red[7]));
    mm[(b * NBX + blockIdx.x) * 2]     = Mx;
    mm[(b * NBX + blockIdx.x) * 2 + 1] = Mn;
  }
}

// Pure elementwise normalizer: out[i] = (cf[i] - mn_b) * rs_b. Same flat index
// for read and write — no layout logic at all.
__global__ __launch_bounds__(256)
void norm_out(const float* __restrict__ cf, const float* __restrict__ mm,
              float* __restrict__ out)
{
  const int b = blockIdx.y;
  float mx = -INFINITY, mn = INFINITY;
  #pragma unroll
  for (int i = 0; i < NBX; ++i) {
    mx = fmaxf(mx, mm[(b * NBX + i) * 2]);
    mn = fminf(mn, mm[(b * NBX + i) * 2 + 1]);
  }
  const float rs = 1.0f / (mx - mn);

  const int c = blockIdx.x * 256 + threadIdx.x;   // f32x4 chunk within batch
  if (c < WOUT * 8) {                             // 8190*32/4 = 65520 chunks
    long base = (long)b * (WOUT * FILT) + (long)c * 4;
    f32x4 v = *reinterpret_cast<const f32x4*>(cf + base);
    f32x4 o;
    o.x = (v.x - mn) * rs;
    o.y = (v.y - mn) * rs;
    o.z = (v.z - mn) * rs;
    o.w = (v.w - mn) * rs;
    *reinterpret_cast<f32x4*>(out + base) = o;
  }
}

extern "C" void kernel_launch(void* const* d_in, const int* in_sizes, int n_in,
                              void* d_out, int out_size, void* d_ws, size_t ws_size,
                              hipStream_t stream) {
  const float* x   = (const float*)d_in[0];
  const float* ker = (const float*)d_in[1];
  float* out = (float*)d_out;
  float* mm  = (float*)d_ws;                       // 1024 floats (4 KB)
  float* cf  = (float*)((char*)d_ws + 4096);       // 134 MB f32 intermediate

  conv_min<<<dim3(NBX, BATCH), dim3(256), 0, stream>>>(x, ker, cf, mm);
  norm_out<<<dim3(256, BATCH), dim3(256), 0, stream>>>(cf, mm, out);
}

// Round 9
// 110.814 us; speedup vs baseline: 2.8561x; 1.2013x over previous
//
#include <hip/hip_runtime.h>
#include <hip/hip_bf16.h>

#define BATCH  128
#define WIDTH  8192
#define DIM    64
#define FILT   32
#define KSZ    3
#define WOUT   8190
#define RPW    30      // output rows per wave per tile
#define WT     120     // output rows per tile (4 waves)
#define TPB    18      // tiles per block
#define NBX    4       // NBX*TPB = 72 tiles >= ceil(8190/120) = 69

typedef __attribute__((ext_vector_type(8))) _Float16 f16x8;
typedef __attribute__((ext_vector_type(4))) float f32x4;
typedef __attribute__((ext_vector_type(4))) unsigned u32x4;

// Conv once: per-block min/max -> mm; conv values packed f16 -> c16.
// c16 viewed as u32 [b][w][16]: slot s holds filters {2s, 2s+1} as {lo,hi} —
// i.e. bit-identical to a flat f16 array [b][w][32].
__global__ __launch_bounds__(256, 2)
void conv_min(const float* __restrict__ x, const float* __restrict__ ker,
              unsigned* __restrict__ c16, float* __restrict__ mm)
{
  // Per-wave private double-buffered x tiles: fp32 [buf][wave][32 rows][64].
  // DMA'd linear; content swizzled: xs[..][row][slot16] = x[row][slot16 ^ (row&7)].
  __shared__ __align__(16) float xs[2][4][32][DIM];   // 64 KB
  __shared__ __align__(16) short ks[KSZ * FILT * DIM]; // f16 [k][f][d], 12 KB
  __shared__ float red[8];

  const int t  = threadIdx.x;
  const int l  = t & 63;
  const int wv = t >> 6;
  const int b  = blockIdx.y;
  const int tile0 = blockIdx.x * TPB;
  const float* xb = x + (long)b * WIDTH * DIM;

  // Per-wave stage: 8 direct-to-LDS DMA (1 KB each) into this wave's region.
  auto stage = [&](int bb, int tile) {
    long gw0 = (long)(tile0 + tile) * WT + wv * RPW;
    char* lb = (char*)&xs[bb][wv][0][0];
    #pragma unroll
    for (int j = 0; j < 8; ++j) {
      int row_l = j * 4 + (l >> 4);
      int slot  = (l & 15) ^ (row_l & 7);
      long gr = gw0 + row_l;
      if (gr > WIDTH - 1) gr = WIDTH - 1;   // tail-tile OOB guard
      __builtin_amdgcn_global_load_lds(
          (const __attribute__((address_space(1))) void*)(xb + gr * DIM + slot * 4),
          (__attribute__((address_space(3))) void*)(lb + j * 1024), 16, 0, 0);
    }
  };

  stage(0, 0);   // prologue prefetch; hides under weight staging

  // ---- weights: fp32 [k][d][f] coalesced -> f16 LDS [k][f][d], XOR-swizzled
  #pragma unroll
  for (int i = 0; i < 24; ++i) {
    int idx = t + i * 256;
    int k = idx >> 11, rem = idx & 2047;
    int d = rem >> 5,  f = rem & 31;
    _Float16 hv = (_Float16)ker[idx];
    int byte = ((k * FILT + f) * DIM + d) * 2;
    byte ^= (f & 7) << 4;
    ks[byte >> 1] = __builtin_bit_cast(short, hv);
  }
  __syncthreads();   // only barrier before epilogue

  // ---- B fragments: 12 frags x 4 VGPR (f16).
  // nt=0 -> EVEN filters {0,2,..,30}, nt=1 -> ODD {1,3,..,31}; MFMA B-column
  // index is lane&15 regardless of which filters we load, so each lane's
  // (nt=0, nt=1) acc pair is filters {2*(l&15), 2*(l&15)+1} — adjacent.
  f16x8 Bf[KSZ][2][2];
  #pragma unroll
  for (int s = 0; s < KSZ; ++s)
    #pragma unroll
    for (int kh = 0; kh < 2; ++kh)
      #pragma unroll
      for (int nt = 0; nt < 2; ++nt) {
        int f  = 2 * (l & 15) + nt;
        int d0 = kh * 32 + (l >> 4) * 8;
        int byte = ((s * FILT + f) * DIM + d0) * 2;
        byte ^= (f & 7) << 4;
        Bf[s][kh][nt] = *reinterpret_cast<const f16x8*>(&ks[byte >> 1]);
      }

  float mx = -INFINITY, mn = INFINITY;

  int cur = 0;
  for (int it = 0; it < TPB; ++it) {
    // T4: counted vmcnt — next tile's loads stay in flight through compute.
    if (it + 1 < TPB) {
      stage(cur ^ 1, it + 1);
      asm volatile("s_waitcnt vmcnt(8)" ::: "memory");
    } else {
      asm volatile("s_waitcnt vmcnt(0)" ::: "memory");
    }
    __builtin_amdgcn_sched_barrier(0);   // rule #18: pin ds_reads after the wait

    const float* xl = &xs[cur][wv][0][0];
    f32x4 acc[2][2];
    #pragma unroll
    for (int mt = 0; mt < 2; ++mt)
      #pragma unroll
      for (int nt = 0; nt < 2; ++nt)
        acc[mt][nt] = (f32x4){0.f, 0.f, 0.f, 0.f};

    #pragma unroll
    for (int s = 0; s < KSZ; ++s) {
      #pragma unroll
      for (int kh = 0; kh < 2; ++kh) {
        f16x8 a[2];
        #pragma unroll
        for (int mt = 0; mt < 2; ++mt) {
          int r  = mt * 16 + (l & 15) + s;   // rows 32..33 bleed into neighbor: masked
          int sg = kh * 8 + (l >> 4) * 2;
          int rb = r & 7;
          f32x4 u0 = *reinterpret_cast<const f32x4*>(&xl[r * DIM + ((sg    ) ^ rb) * 4]);
          f32x4 u1 = *reinterpret_cast<const f32x4*>(&xl[r * DIM + ((sg + 1) ^ rb) * 4]);
          f16x8 av;
          av[0] = (_Float16)u0.x; av[1] = (_Float16)u0.y;
          av[2] = (_Float16)u0.z; av[3] = (_Float16)u0.w;
          av[4] = (_Float16)u1.x; av[5] = (_Float16)u1.y;
          av[6] = (_Float16)u1.z; av[7] = (_Float16)u1.w;
          a[mt] = av;
        }
        #pragma unroll
        for (int mt = 0; mt < 2; ++mt)
          #pragma unroll
          for (int nt = 0; nt < 2; ++nt)
            acc[mt][nt] = __builtin_amdgcn_mfma_f32_16x16x32_f16(
                a[mt], Bf[s][kh][nt], acc[mt][nt], 0, 0, 0);
      }
    }

    // Epilogue: round-8 addressing; pack {even,odd} filter pair explicitly.
    long w0t = (long)(tile0 + it) * WT + wv * RPW;
    #pragma unroll
    for (int mt = 0; mt < 2; ++mt)
      #pragma unroll
      for (int r = 0; r < 4; ++r) {
        int wl = mt * 16 + (l >> 4) * 4 + r;   // C-row = (lane>>4)*4+reg
        long gr = w0t + wl;
        if (wl < RPW && gr < WOUT) {
          float v0 = acc[mt][0][r];            // filter 2*(l&15)
          float v1 = acc[mt][1][r];            // filter 2*(l&15)+1
          mx = fmaxf(mx, fmaxf(v0, v1));
          mn = fminf(mn, fminf(v0, v1));
          unsigned lo = __builtin_bit_cast(unsigned short, (_Float16)v0);
          unsigned hi = __builtin_bit_cast(unsigned short, (_Float16)v1);
          c16[((long)b * WOUT + gr) * 16 + (l & 15)] = lo | (hi << 16);
        }
      }
    cur ^= 1;
  }

  #pragma unroll
  for (int off = 32; off > 0; off >>= 1) {
    mx = fmaxf(mx, __shfl_down(mx, off));
    mn = fminf(mn, __shfl_down(mn, off));
  }
  if (l == 0) { red[wv * 2] = mx; red[wv * 2 + 1] = mn; }
  __syncthreads();
  if (t == 0) {
    float Mx = fmaxf(fmaxf(red[0], red[2]), fmaxf(red[4], red[6]));
    float Mn = fminf(fminf(red[1], red[3]), fminf(red[5], red[7]));
    mm[(b * NBX + blockIdx.x) * 2]     = Mx;
    mm[(b * NBX + blockIdx.x) * 2 + 1] = Mn;
  }
}

// Flat normalizer: c16 is a flat f16 array [b][w][32]; u32x4 chunk c covers
// f16 flat indices [c*8, c*8+8) -> 8 consecutive f32 outputs at the same
// flat position. No layout decomposition.
__global__ __launch_bounds__(256)
void norm_out(const unsigned* __restrict__ c16, const float* __restrict__ mm,
              float* __restrict__ out)
{
  const int b = blockIdx.y;
  float mx = -INFINITY, mn = INFINITY;
  #pragma unroll
  for (int i = 0; i < NBX; ++i) {
    mx = fmaxf(mx, mm[(b * NBX + i) * 2]);
    mn = fminf(mn, mm[(b * NBX + i) * 2 + 1]);
  }
  const float rs = 1.0f / (mx - mn);

  const int c = blockIdx.x * 256 + threadIdx.x;   // u32x4 chunk within batch
  if (c < WOUT * 4) {                             // 8190*16/4 = 32760 chunks
    u32x4 v = *reinterpret_cast<const u32x4*>(c16 + ((long)b * WOUT) * 16 + (long)c * 4);
    long base = (long)b * (WOUT * FILT) + (long)c * 8;
    f32x4 o0, o1;
    #pragma unroll
    for (int j = 0; j < 2; ++j) {
      unsigned u = v[j];
      o0[2*j]   = ((float)__builtin_bit_cast(_Float16, (unsigned short)(u & 0xffffu)) - mn) * rs;
      o0[2*j+1] = ((float)__builtin_bit_cast(_Float16, (unsigned short)(u >> 16))      - mn) * rs;
    }
    #pragma unroll
    for (int j = 0; j < 2; ++j) {
      unsigned u = v[2+j];
      o1[2*j]   = ((float)__builtin_bit_cast(_Float16, (unsigned short)(u & 0xffffu)) - mn) * rs;
      o1[2*j+1] = ((float)__builtin_bit_cast(_Float16, (unsigned short)(u >> 16))      - mn) * rs;
    }
    *reinterpret_cast<f32x4*>(out + base)     = o0;
    *reinterpret_cast<f32x4*>(out + base + 4) = o1;
  }
}

extern "C" void kernel_launch(void* const* d_in, const int* in_sizes, int n_in,
                              void* d_out, int out_size, void* d_ws, size_t ws_size,
                              hipStream_t stream) {
  const float* x   = (const float*)d_in[0];
  const float* ker = (const float*)d_in[1];
  float* out = (float*)d_out;
  float*    mm  = (float*)d_ws;                       // 1024 floats (4 KB)
  unsigned* c16 = (unsigned*)((char*)d_ws + 4096);    // 67 MB f16-pair intermediate

  conv_min<<<dim3(NBX, BATCH), dim3(256), 0, stream>>>(x, ker, c16, mm);
  norm_out<<<dim3(128, BATCH), dim3(256), 0, stream>>>(c16, mm, out);
}

// Round 10
// 110.649 us; speedup vs baseline: 2.8603x; 1.0015x over previous
//
#include <hip/hip_runtime.h>
#include <hip/hip_bf16.h>

#define BATCH  128
#define WIDTH  8192
#define DIM    64
#define FILT   32
#define KSZ    3
#define WOUT   8190
#define RPW    14      // output rows per wave per step
#define RST    16      // rows staged per wave per step
#define NW     8       // waves per block (512 threads)
#define WT     112     // NW*RPW output rows per block-step
#define TPB    19      // steps per block
#define NBX    4       // 4*19*112 = 8512 >= 8190
#define XROWS  (NW*RST + 2)   // 130 rows per buffer (2 pad rows: garbage, masked)

typedef __attribute__((ext_vector_type(8))) _Float16 f16x8;
typedef __attribute__((ext_vector_type(4))) float f32x4;
typedef __attribute__((ext_vector_type(4))) unsigned u32x4;

// Conv once: per-block min/max -> mm; conv values packed f16 -> c16.
// c16 viewed as u32 [b][w][16]: slot s holds filters {2s,2s+1} = flat f16 [b][w][32].
__global__ __launch_bounds__(512, 4)
void conv_min(const float* __restrict__ x, const float* __restrict__ ker,
              unsigned* __restrict__ c16, float* __restrict__ mm)
{
  // Per-wave private double-buffered x rows: fp32, rows r of buffer = wave (r/16).
  // DMA'd linear; content swizzled: xs[..][row][slot16] = x[row][slot16 ^ (row&7)].
  __shared__ __align__(16) float xs[2][XROWS * DIM];   // 66.6 KB
  __shared__ __align__(16) short ks[KSZ * FILT * DIM]; // f16 [k][f][d], 12 KB
  __shared__ float red[2 * NW];

  const int t  = threadIdx.x;
  const int l  = t & 63;
  const int wv = t >> 6;
  const int b  = blockIdx.y;
  const int step0 = blockIdx.x * TPB;
  const float* xb = x + (long)b * WIDTH * DIM;

  // Per-wave stage: 4 direct-to-LDS DMA (1 KB = 4 rows each) into wave's region.
  auto stage = [&](int bb, int step) {
    long gw0 = (long)(step0 + step) * WT + wv * RPW;
    char* lb = (char*)&xs[bb][0] + wv * (RST * DIM * 4);
    #pragma unroll
    for (int j = 0; j < 4; ++j) {
      int row_l = j * 4 + (l >> 4);
      int slot  = (l & 15) ^ (row_l & 7);
      long gr = gw0 + row_l;
      if (gr > WIDTH - 1) gr = WIDTH - 1;   // tail OOB guard (dup reads, L2-hot)
      __builtin_amdgcn_global_load_lds(
          (const __attribute__((address_space(1))) void*)(xb + gr * DIM + slot * 4),
          (__attribute__((address_space(3))) void*)(lb + j * 1024), 16, 0, 0);
    }
  };

  stage(0, 0);   // prologue prefetch; hides under weight staging

  // ---- weights: fp32 [k][d][f] coalesced -> f16 LDS [k][f][d], XOR-swizzled
  #pragma unroll
  for (int i = 0; i < 12; ++i) {
    int idx = t + i * 512;
    int k = idx >> 11, rem = idx & 2047;
    int d = rem >> 5,  f = rem & 31;
    _Float16 hv = (_Float16)ker[idx];
    int byte = ((k * FILT + f) * DIM + d) * 2;
    byte ^= (f & 7) << 4;
    ks[byte >> 1] = __builtin_bit_cast(short, hv);
  }
  __syncthreads();   // drains weights + step-0 DMA; only barrier before epilogue

  // ---- B fragments (r9 even/odd layout): nt=0 -> filter 2*(l&15), nt=1 -> +1
  f16x8 Bf[KSZ][2][2];
  #pragma unroll
  for (int s = 0; s < KSZ; ++s)
    #pragma unroll
    for (int kh = 0; kh < 2; ++kh)
      #pragma unroll
      for (int nt = 0; nt < 2; ++nt) {
        int f  = 2 * (l & 15) + nt;
        int d0 = kh * 32 + (l >> 4) * 8;
        int byte = ((s * FILT + f) * DIM + d0) * 2;
        byte ^= (f & 7) << 4;
        Bf[s][kh][nt] = *reinterpret_cast<const f16x8*>(&ks[byte >> 1]);
      }

  float mx = -INFINITY, mn = INFINITY;

  int cur = 0;
  for (int it = 0; it < TPB; ++it) {
    // Counted vmcnt sized so fresh stores stay in the allowed window:
    // newest 8 = S(it-1)[4] + L(it+1)[4]; in-order retirement then guarantees
    // L(it) (this step's buffer) is complete WITHOUT waiting on S(it-1).
    if (it + 1 < TPB) {
      stage(cur ^ 1, it + 1);
      asm volatile("s_waitcnt vmcnt(8)" ::: "memory");
    } else {
      asm volatile("s_waitcnt vmcnt(4)" ::: "memory");   // newest 4 = S(T-2)
    }
    __builtin_amdgcn_sched_barrier(0);   // rule #18: pin ds_reads after the wait

    const float* xl = &xs[cur][0];
    f32x4 acc[2];
    acc[0] = (f32x4){0.f, 0.f, 0.f, 0.f};
    acc[1] = (f32x4){0.f, 0.f, 0.f, 0.f};

    #pragma unroll
    for (int s = 0; s < KSZ; ++s) {
      #pragma unroll
      for (int kh = 0; kh < 2; ++kh) {
        // fragment rows 14..17 (l&15>=14) feed only masked C rows 14,15
        int ra = wv * RST + (l & 15) + s;
        int sg = kh * 8 + (l >> 4) * 2;
        int rb = ra & 7;
        f32x4 u0 = *reinterpret_cast<const f32x4*>(&xl[ra * DIM + ((sg    ) ^ rb) * 4]);
        f32x4 u1 = *reinterpret_cast<const f32x4*>(&xl[ra * DIM + ((sg + 1) ^ rb) * 4]);
        u32x4 pk;
        pk.x = __builtin_bit_cast(unsigned, __builtin_amdgcn_cvt_pkrtz(u0.x, u0.y));
        pk.y = __builtin_bit_cast(unsigned, __builtin_amdgcn_cvt_pkrtz(u0.z, u0.w));
        pk.z = __builtin_bit_cast(unsigned, __builtin_amdgcn_cvt_pkrtz(u1.x, u1.y));
        pk.w = __builtin_bit_cast(unsigned, __builtin_amdgcn_cvt_pkrtz(u1.z, u1.w));
        f16x8 av = __builtin_bit_cast(f16x8, pk);
        acc[0] = __builtin_amdgcn_mfma_f32_16x16x32_f16(av, Bf[s][kh][0], acc[0], 0, 0, 0);
        acc[1] = __builtin_amdgcn_mfma_f32_16x16x32_f16(av, Bf[s][kh][1], acc[1], 0, 0, 0);
      }
    }

    long gw0 = (long)(step0 + it) * WT + wv * RPW;
    #pragma unroll
    for (int r = 0; r < 4; ++r) {
      int wl = (l >> 4) * 4 + r;    // C-row = (lane>>4)*4+reg
      long gr = gw0 + wl;
      if (wl < RPW && gr < WOUT) {
        float v0 = acc[0][r];       // filter 2*(l&15)
        float v1 = acc[1][r];       // filter 2*(l&15)+1
        mx = fmaxf(mx, fmaxf(v0, v1));
        mn = fminf(mn, fminf(v0, v1));
        unsigned lo = __builtin_bit_cast(unsigned short, (_Float16)v0);
        unsigned hi = __builtin_bit_cast(unsigned short, (_Float16)v1);
        c16[((long)b * WOUT + gr) * 16 + (l & 15)] = lo | (hi << 16);
      }
    }
    cur ^= 1;
  }

  #pragma unroll
  for (int off = 32; off > 0; off >>= 1) {
    mx = fmaxf(mx, __shfl_down(mx, off));
    mn = fminf(mn, __shfl_down(mn, off));
  }
  if (l == 0) { red[wv * 2] = mx; red[wv * 2 + 1] = mn; }
  __syncthreads();
  if (t == 0) {
    float Mx = -INFINITY, Mn = INFINITY;
    #pragma unroll
    for (int w = 0; w < NW; ++w) {
      Mx = fmaxf(Mx, red[w * 2]);
      Mn = fminf(Mn, red[w * 2 + 1]);
    }
    mm[(b * NBX + blockIdx.x) * 2]     = Mx;
    mm[(b * NBX + blockIdx.x) * 2 + 1] = Mn;
  }
}

// Flat normalizer (unchanged from r9): c16 = flat f16 [b][w][32]; chunk c covers
// f16 indices [c*8, c*8+8) -> 8 consecutive f32 outputs at the same flat position.
__global__ __launch_bounds__(256)
void norm_out(const unsigned* __restrict__ c16, const float* __restrict__ mm,
              float* __restrict__ out)
{
  const int b = blockIdx.y;
  float mx = -INFINITY, mn = INFINITY;
  #pragma unroll
  for (int i = 0; i < NBX; ++i) {
    mx = fmaxf(mx, mm[(b * NBX + i) * 2]);
    mn = fminf(mn, mm[(b * NBX + i) * 2 + 1]);
  }
  const float rs = 1.0f / (mx - mn);

  const int c = blockIdx.x * 256 + threadIdx.x;   // u32x4 chunk within batch
  if (c < WOUT * 4) {                             // 8190*16/4 = 32760 chunks
    u32x4 v = *reinterpret_cast<const u32x4*>(c16 + ((long)b * WOUT) * 16 + (long)c * 4);
    long base = (long)b * (WOUT * FILT) + (long)c * 8;
    f32x4 o0, o1;
    #pragma unroll
    for (int j = 0; j < 2; ++j) {
      unsigned u = v[j];
      o0[2*j]   = ((float)__builtin_bit_cast(_Float16, (unsigned short)(u & 0xffffu)) - mn) * rs;
      o0[2*j+1] = ((float)__builtin_bit_cast(_Float16, (unsigned short)(u >> 16))      - mn) * rs;
    }
    #pragma unroll
    for (int j = 0; j < 2; ++j) {
      unsigned u = v[2+j];
      o1[2*j]   = ((float)__builtin_bit_cast(_Float16, (unsigned short)(u & 0xffffu)) - mn) * rs;
      o1[2*j+1] = ((float)__builtin_bit_cast(_Float16, (unsigned short)(u >> 16))      - mn) * rs;
    }
    *reinterpret_cast<f32x4*>(out + base)     = o0;
    *reinterpret_cast<f32x4*>(out + base + 4) = o1;
  }
}

extern "C" void kernel_launch(void* const* d_in, const int* in_sizes, int n_in,
                              void* d_out, int out_size, void* d_ws, size_t ws_size,
                              hipStream_t stream) {
  const float* x   = (const float*)d_in[0];
  const float* ker = (const float*)d_in[1];
  float* out = (float*)d_out;
  float*    mm  = (float*)d_ws;                       // 1024 floats (4 KB)
  unsigned* c16 = (unsigned*)((char*)d_ws + 4096);    // 67 MB f16-pair intermediate

  conv_min<<<dim3(NBX, BATCH), dim3(512), 0, stream>>>(x, ker, c16, mm);
  norm_out<<<dim3(128, BATCH), dim3(256), 0, stream>>>(c16, mm, out);
}